// Round 13
// baseline (164.693 us; speedup 1.0000x reference)
//
#include <hip/hip_runtime.h>
#include <hip/hip_bf16.h>

#define NROW 131072   // B*L
#define D 256
#define K 320
#define BN_EPS 1e-5f
#define FIXSCALE 16777216.0f   // 2^24 fixed-point for deterministic atomics

typedef _Float16 half8 __attribute__((ext_vector_type(8)));
typedef float f32x4 __attribute__((ext_vector_type(4)));

// ws layout:
//   u64 acc[512]   @ 0      (4 KB)
//   f32 meanb[256] @ 4096
//   f32 rsb[256]   @ 5120
//   f32 cnorm[320] @ 6144
//   f16 cbx        @ 8192   (320 KB) codebook fragments, chunk-contiguous:
//     tile nt(0..19), hl(0=hi,1=lo), ks(0..7): halfs at ((nt*2+hl)*8+ks)*512 + lane*8
//     -> chunk c (tiles 2c,2c+1) is the contiguous 32 KB at c*32768 bytes

// ---------------- kernel 0: zero the fixed-point accumulators ---------------
__global__ __launch_bounds__(256) void k_zero(unsigned long long* __restrict__ acc) {
  acc[threadIdx.x] = 0ull;
  acc[256 + threadIdx.x] = 0ull;
}

// ---------------- kernel 1: per-block channel partials -> fixed-point atomics
__global__ __launch_bounds__(256) void k_stats_partial(const float* __restrict__ x,
                                                       unsigned long long* __restrict__ acc) {
  const int d = threadIdx.x;
  const int blk = blockIdx.x;         // 512 blocks, 256 rows each
  const float* p = x + (size_t)blk * 256 * D + d;
  float s = 0.f, q = 0.f;
  #pragma unroll 4
  for (int r = 0; r < 256; ++r) {
    float v = p[(size_t)r * D];
    s += v;
    q = fmaf(v, v, q);
  }
  long long si = llrintf(s * FIXSCALE);
  long long qi = llrintf(q * FIXSCALE);
  atomicAdd(&acc[d],       (unsigned long long)si);
  atomicAdd(&acc[256 + d], (unsigned long long)qi);
}

// ---------------- kernel 2: finalize stats + codebook norms -----------------
__global__ __launch_bounds__(256) void k_stats_final(const unsigned long long* __restrict__ acc,
                                                     const float* __restrict__ cb,
                                                     float* __restrict__ meanb,
                                                     float* __restrict__ rsb,
                                                     float* __restrict__ cnorm) {
  const int t = threadIdx.x;
  if (blockIdx.x == 0) {
    double s = (double)(long long)acc[t]       / (double)FIXSCALE;
    double q = (double)(long long)acc[256 + t] / (double)FIXSCALE;
    double mean = s / (double)NROW;
    double var  = q / (double)NROW - mean * mean;
    meanb[t] = (float)mean;
    rsb[t]   = (float)(1.0 / sqrt(var + (double)BN_EPS));
  } else {
    for (int code = t; code < K; code += 256) {
      const float* c = cb + (size_t)code * D;
      float s = 0.f;
      for (int dd = 0; dd < D; ++dd) s = fmaf(c[dd], c[dd], s);
      cnorm[code] = s;
    }
  }
}

// ---------------- kernel 2b: split codebook to fp16 hi/lo fragments ---------
// MFMA B-fragment: lane l holds code = nt*16 + (l&15), k = ks*32 + (l>>4)*8..+8
__global__ __launch_bounds__(64) void k_cbprep(const float* __restrict__ cb,
                                               _Float16* __restrict__ cbx) {
  const int nt = blockIdx.x;   // 0..19
  const int ks = blockIdx.y;   // 0..7
  const int l  = threadIdx.x;  // 0..63
  const int code = nt * 16 + (l & 15);
  const int d0 = ks * 32 + (l >> 4) * 8;
  const float* src = cb + (size_t)code * D + d0;
  const size_t bh = ((size_t)(nt * 2 + 0) * 8 + ks) * 512 + l * 8;
  const size_t bl = ((size_t)(nt * 2 + 1) * 8 + ks) * 512 + l * 8;
  #pragma unroll
  for (int j = 0; j < 8; ++j) {
    float v = src[j];
    _Float16 h = (_Float16)v;
    _Float16 lo = (_Float16)(v - (float)h);
    cbx[bh + j] = h;
    cbx[bl + j] = lo;
  }
}

// ---------------- kernel 3: A-in-registers (32 rows/wave), 4-slot B pipeline
// 512 blocks x 512 thr, 1 block/CU. Wave wv owns rows row0+wv*32..+32 vs ALL
// 320 codes. 4 LDS chunk slots; each phase computes chunks {c,c+1} (slots
// c&3,(c+1)&3) and stages {c+2,c+3} into the OTHER two slots -> zero
// intra-phase hazards, one barrier per 2 chunks.
__global__ __launch_bounds__(512) void k_main(const float* __restrict__ x,
                                              const float* __restrict__ w,
                                              const float* __restrict__ bias,
                                              const float* __restrict__ cb,
                                              const float* __restrict__ meanb,
                                              const float* __restrict__ rsb,
                                              const float* __restrict__ cnorm,
                                              const _Float16* __restrict__ cbx,
                                              float* __restrict__ out) {
  __shared__ _Float16 Bbuf[4][16384];   // 4 x 32 KB code-chunk slots (128 KB)
  __shared__ float sxs[256];            // per-row |xb|^2
  __shared__ int bsel[256];

  const int t = threadIdx.x;
  const int lane = t & 63;
  const int wv = t >> 6;              // wave 0..7
  const int c15 = lane & 15;
  const int g = lane >> 4;
  const int row0 = (int)blockIdx.x * 256;

  // ---- cooperative B staging: chunk c = 32 KB contiguous, reg-staged ----
  float4 s0, s1, s2, s3;
  const char* stg_src = (const char*)cbx + (size_t)t * 16;
#define ISSUE(c) {                                                  \
    const char* p_ = stg_src + (size_t)(c) * 32768;                 \
    s0 = *(const float4*)(p_);                                      \
    s1 = *(const float4*)(p_ + 8192);                               \
    s2 = *(const float4*)(p_ + 16384);                              \
    s3 = *(const float4*)(p_ + 24576);                              \
  }
#define WRITE(b) {                                                  \
    char* q_ = (char*)Bbuf[(b)] + t * 16;                           \
    *(float4*)(q_)         = s0;                                    \
    *(float4*)(q_ + 8192)  = s1;                                    \
    *(float4*)(q_ + 16384) = s2;                                    \
    *(float4*)(q_ + 24576) = s3;                                    \
  }

  ISSUE(0);

  // ---- x -> A fragments in registers (normalize + fp16 hi/lo split) ----
  // lane l, tile i: row = row0 + wv*32 + i*16 + (l&15), dims g*8 + ks*32 ..+8
  half8 ah[2][8], al[2][8];
  float accq0 = 0.f, accq1 = 0.f;
  {
    const int dbase = g * 8;
    const float* xp0 = x + (size_t)(row0 + wv * 32 + c15) * D + dbase;
    const float* xp1 = x + (size_t)(row0 + wv * 32 + 16 + c15) * D + dbase;
    #pragma unroll
    for (int ks = 0; ks < 8; ++ks) {
      const int d0 = dbase + ks * 32;
      float4 m0 = *(const float4*)(meanb + d0);
      float4 m1 = *(const float4*)(meanb + d0 + 4);
      float4 r0 = *(const float4*)(rsb + d0);
      float4 r1 = *(const float4*)(rsb + d0 + 4);
      float4 w0 = *(const float4*)(w + d0);
      float4 w1 = *(const float4*)(w + d0 + 4);
      float4 b0 = *(const float4*)(bias + d0);
      float4 b1 = *(const float4*)(bias + d0 + 4);
      // tile 0
      {
        float4 xa = *(const float4*)(xp0 + ks * 32);
        float4 xb2 = *(const float4*)(xp0 + ks * 32 + 4);
        float o0 = ((xa.x - m0.x) * r0.x) * w0.x + b0.x;
        float o1 = ((xa.y - m0.y) * r0.y) * w0.y + b0.y;
        float o2 = ((xa.z - m0.z) * r0.z) * w0.z + b0.z;
        float o3 = ((xa.w - m0.w) * r0.w) * w0.w + b0.w;
        float o4 = ((xb2.x - m1.x) * r1.x) * w1.x + b1.x;
        float o5 = ((xb2.y - m1.y) * r1.y) * w1.y + b1.y;
        float o6 = ((xb2.z - m1.z) * r1.z) * w1.z + b1.z;
        float o7 = ((xb2.w - m1.w) * r1.w) * w1.w + b1.w;
        accq0 = fmaf(o0, o0, accq0); accq0 = fmaf(o1, o1, accq0);
        accq0 = fmaf(o2, o2, accq0); accq0 = fmaf(o3, o3, accq0);
        accq0 = fmaf(o4, o4, accq0); accq0 = fmaf(o5, o5, accq0);
        accq0 = fmaf(o6, o6, accq0); accq0 = fmaf(o7, o7, accq0);
        _Float16 h;
        h = (_Float16)o0; ah[0][ks][0] = h; al[0][ks][0] = (_Float16)(o0 - (float)h);
        h = (_Float16)o1; ah[0][ks][1] = h; al[0][ks][1] = (_Float16)(o1 - (float)h);
        h = (_Float16)o2; ah[0][ks][2] = h; al[0][ks][2] = (_Float16)(o2 - (float)h);
        h = (_Float16)o3; ah[0][ks][3] = h; al[0][ks][3] = (_Float16)(o3 - (float)h);
        h = (_Float16)o4; ah[0][ks][4] = h; al[0][ks][4] = (_Float16)(o4 - (float)h);
        h = (_Float16)o5; ah[0][ks][5] = h; al[0][ks][5] = (_Float16)(o5 - (float)h);
        h = (_Float16)o6; ah[0][ks][6] = h; al[0][ks][6] = (_Float16)(o6 - (float)h);
        h = (_Float16)o7; ah[0][ks][7] = h; al[0][ks][7] = (_Float16)(o7 - (float)h);
      }
      // tile 1
      {
        float4 xa = *(const float4*)(xp1 + ks * 32);
        float4 xb2 = *(const float4*)(xp1 + ks * 32 + 4);
        float o0 = ((xa.x - m0.x) * r0.x) * w0.x + b0.x;
        float o1 = ((xa.y - m0.y) * r0.y) * w0.y + b0.y;
        float o2 = ((xa.z - m0.z) * r0.z) * w0.z + b0.z;
        float o3 = ((xa.w - m0.w) * r0.w) * w0.w + b0.w;
        float o4 = ((xb2.x - m1.x) * r1.x) * w1.x + b1.x;
        float o5 = ((xb2.y - m1.y) * r1.y) * w1.y + b1.y;
        float o6 = ((xb2.z - m1.z) * r1.z) * w1.z + b1.z;
        float o7 = ((xb2.w - m1.w) * r1.w) * w1.w + b1.w;
        accq1 = fmaf(o0, o0, accq1); accq1 = fmaf(o1, o1, accq1);
        accq1 = fmaf(o2, o2, accq1); accq1 = fmaf(o3, o3, accq1);
        accq1 = fmaf(o4, o4, accq1); accq1 = fmaf(o5, o5, accq1);
        accq1 = fmaf(o6, o6, accq1); accq1 = fmaf(o7, o7, accq1);
        _Float16 h;
        h = (_Float16)o0; ah[1][ks][0] = h; al[1][ks][0] = (_Float16)(o0 - (float)h);
        h = (_Float16)o1; ah[1][ks][1] = h; al[1][ks][1] = (_Float16)(o1 - (float)h);
        h = (_Float16)o2; ah[1][ks][2] = h; al[1][ks][2] = (_Float16)(o2 - (float)h);
        h = (_Float16)o3; ah[1][ks][3] = h; al[1][ks][3] = (_Float16)(o3 - (float)h);
        h = (_Float16)o4; ah[1][ks][4] = h; al[1][ks][4] = (_Float16)(o4 - (float)h);
        h = (_Float16)o5; ah[1][ks][5] = h; al[1][ks][5] = (_Float16)(o5 - (float)h);
        h = (_Float16)o6; ah[1][ks][6] = h; al[1][ks][6] = (_Float16)(o6 - (float)h);
        h = (_Float16)o7; ah[1][ks][7] = h; al[1][ks][7] = (_Float16)(o7 - (float)h);
      }
    }
  }

  WRITE(0);                           // slot0 <- chunk0
  ISSUE(1);

  // row sums: butterfly over the 4 k-slices (lanes xor 16, 32); deterministic
  {
    float v0 = accq0 + __shfl_xor(accq0, 16);
    float sx0 = v0 + __shfl_xor(v0, 32);
    float v1 = accq1 + __shfl_xor(accq1, 16);
    float sx1 = v1 + __shfl_xor(v1, 32);
    if (lane < 16) {
      sxs[wv * 32 + lane]      = sx0;
      sxs[wv * 32 + 16 + lane] = sx1;
    }
  }

  WRITE(1);                           // slot1 <- chunk1
  ISSUE(2);                           // chunk2 in flight across the barrier
  __syncthreads();                    // slots 0,1 + sxs visible

  // ---- chunk-pair loop: 5 phases x 2 chunks; argmin folded per chunk ----
  float bv[2][4];
  int   bix[2][4];
  #pragma unroll
  for (int i = 0; i < 2; ++i)
    #pragma unroll
    for (int r = 0; r < 4; ++r) { bv[i][r] = 3.4e38f; bix[i][r] = 0x7fffffff; }

  float sxr[2][4];
  #pragma unroll
  for (int i = 0; i < 2; ++i)
    #pragma unroll
    for (int r = 0; r < 4; ++r) sxr[i][r] = sxs[wv * 32 + i * 16 + g * 4 + r];

#define COMPUTE(cc) {                                                          \
    const _Float16* bb = Bbuf[(cc) & 3] + lane * 8;                            \
    f32x4 acc[2][2];                                                           \
    _Pragma("unroll")                                                          \
    for (int i = 0; i < 2; ++i)                                                \
      _Pragma("unroll")                                                        \
      for (int tt = 0; tt < 2; ++tt) acc[i][tt] = (f32x4){0.f, 0.f, 0.f, 0.f};\
    _Pragma("unroll")                                                          \
    for (int tt = 0; tt < 2; ++tt) {                                           \
      _Pragma("unroll")                                                        \
      for (int ks = 0; ks < 8; ++ks) {                                         \
        half8 bh = *(const half8*)(bb + ((tt * 2 + 0) * 8 + ks) * 512);        \
        half8 bl = *(const half8*)(bb + ((tt * 2 + 1) * 8 + ks) * 512);        \
        _Pragma("unroll")                                                      \
        for (int i = 0; i < 2; ++i) {                                          \
          acc[i][tt] = __builtin_amdgcn_mfma_f32_16x16x32_f16(ah[i][ks], bh, acc[i][tt], 0, 0, 0); \
          acc[i][tt] = __builtin_amdgcn_mfma_f32_16x16x32_f16(ah[i][ks], bl, acc[i][tt], 0, 0, 0); \
          acc[i][tt] = __builtin_amdgcn_mfma_f32_16x16x32_f16(al[i][ks], bh, acc[i][tt], 0, 0, 0); \
        }                                                                      \
      }                                                                        \
    }                                                                          \
    _Pragma("unroll")                                                          \
    for (int tt = 0; tt < 2; ++tt) {                                           \
      const int code = (cc) * 32 + tt * 16 + c15;                              \
      const float cn = cnorm[code];                                            \
      _Pragma("unroll")                                                        \
      for (int i = 0; i < 2; ++i) {                                            \
        _Pragma("unroll")                                                      \
        for (int r = 0; r < 4; ++r) {                                          \
          const float d2 = (sxr[i][r] - 2.0f * acc[i][tt][r]) + cn;            \
          if (d2 < bv[i][r] || (d2 == bv[i][r] && code < bix[i][r])) {         \
            bv[i][r] = d2; bix[i][r] = code;                                   \
          }                                                                    \
        }                                                                      \
      }                                                                        \
    }                                                                          \
  }

  for (int p = 0; p < 5; ++p) {
    const int c = 2 * p;
    if (c + 2 < 10) WRITE((c + 2) & 3);   // s holds chunk c+2 (issued last phase)
    if (c + 3 < 10) ISSUE(c + 3);
    COMPUTE(c);
    if (c + 3 < 10) WRITE((c + 3) & 3);   // vmcnt wait hidden under COMPUTE(c)
    if (c + 4 < 10) ISSUE(c + 4);
    COMPUTE(c + 1);
    if (p < 4) __syncthreads();           // slots c+2, c+3 visible next phase
  }
#undef COMPUTE

  // ---- butterfly argmin across the 16 lanes (columns) ----
  #pragma unroll
  for (int off = 8; off >= 1; off >>= 1) {
    #pragma unroll
    for (int i = 0; i < 2; ++i)
      #pragma unroll
      for (int r = 0; r < 4; ++r) {
        const float ov = __shfl_xor(bv[i][r], off);
        const int   oi = __shfl_xor(bix[i][r], off);
        if (ov < bv[i][r] || (ov == bv[i][r] && oi < bix[i][r])) {
          bv[i][r] = ov; bix[i][r] = oi;
        }
      }
  }
  if (c15 == 0) {
    #pragma unroll
    for (int i = 0; i < 2; ++i)
      #pragma unroll
      for (int r = 0; r < 4; ++r) {
        const int row = wv * 32 + i * 16 + g * 4 + r;   // local row 0..255
        bsel[row] = bix[i][r];
        out[(size_t)NROW * D + row0 + row] = (float)bix[i][r];
      }
  }
  __syncthreads();

  // ---- gather chosen codes (exact f32 copy), 2 threads per row, FULL row ---
  {
    const int lr = t >> 1;            // 0..255
    const int q = t & 1;
    const int code = bsel[lr];
    const float* cp = cb + (size_t)code * D;
    float* op = out + (size_t)(row0 + lr) * D;
    #pragma unroll
    for (int e = 0; e < 32; ++e) {    // 32 float4 per thread x 2 = 256 floats
      *(float4*)(op + (e * 2 + q) * 4) = *(const float4*)(cp + (e * 2 + q) * 4);
    }
  }
#undef ISSUE
#undef WRITE
}

extern "C" void kernel_launch(void* const* d_in, const int* in_sizes, int n_in,
                              void* d_out, int out_size, void* d_ws, size_t ws_size,
                              hipStream_t stream) {
  const float* x    = (const float*)d_in[0];
  const float* w    = (const float*)d_in[1];
  const float* bias = (const float*)d_in[2];
  const float* cb   = (const float*)d_in[3];
  float* out = (float*)d_out;

  unsigned long long* acc = (unsigned long long*)d_ws;
  float* meanb = (float*)((char*)d_ws + 4096);
  float* rsb   = meanb + 256;
  float* cnorm = rsb + 256;
  _Float16* cbx = (_Float16*)((char*)d_ws + 8192);   // 320 KB

  k_zero<<<1, 256, 0, stream>>>(acc);
  k_cbprep<<<dim3(20, 8), 64, 0, stream>>>(cb, cbx);
  k_stats_partial<<<512, 256, 0, stream>>>(x, acc);
  k_stats_final<<<2, 256, 0, stream>>>(acc, cb, meanb, rsb, cnorm);
  k_main<<<NROW / 256, 512, 0, stream>>>(x, w, bias, cb, meanb, rsb, cnorm, cbx, out);
}

// Round 14
// 146.379 us; speedup vs baseline: 1.1251x; 1.1251x over previous
//
#include <hip/hip_runtime.h>
#include <hip/hip_bf16.h>

#define NROW 131072   // B*L
#define D 256
#define K 320
#define BN_EPS 1e-5f
#define FIXSCALE 16777216.0f   // 2^24 fixed-point for deterministic atomics

typedef _Float16 half8 __attribute__((ext_vector_type(8)));
typedef float f32x4 __attribute__((ext_vector_type(4)));

// ws layout:
//   u64 acc[512]   @ 0      (4 KB)
//   f32 meanb[256] @ 4096
//   f32 rsb[256]   @ 5120
//   f32 cnorm[320] @ 6144
//   f16 cbx        @ 8192   (320 KB) codebook fragments:
//     tile nt(0..19) = 16 codes, hl(0=hi,1=lo), ks(0..7):
//     halfs at ((nt*2+hl)*8+ks)*512 + lane*8  -> tile nt = 16 KB at nt*16384 B

// ---------------- kernel 0: zero the fixed-point accumulators ---------------
__global__ __launch_bounds__(256) void k_zero(unsigned long long* __restrict__ acc) {
  acc[threadIdx.x] = 0ull;
  acc[256 + threadIdx.x] = 0ull;
}

// ---------------- kernel 1: per-block channel partials -> fixed-point atomics
__global__ __launch_bounds__(256) void k_stats_partial(const float* __restrict__ x,
                                                       unsigned long long* __restrict__ acc) {
  const int d = threadIdx.x;
  const int blk = blockIdx.x;         // 512 blocks, 256 rows each
  const float* p = x + (size_t)blk * 256 * D + d;
  float s = 0.f, q = 0.f;
  #pragma unroll 4
  for (int r = 0; r < 256; ++r) {
    float v = p[(size_t)r * D];
    s += v;
    q = fmaf(v, v, q);
  }
  long long si = llrintf(s * FIXSCALE);
  long long qi = llrintf(q * FIXSCALE);
  atomicAdd(&acc[d],       (unsigned long long)si);
  atomicAdd(&acc[256 + d], (unsigned long long)qi);
}

// ---------------- kernel 2: finalize stats + codebook norms -----------------
__global__ __launch_bounds__(256) void k_stats_final(const unsigned long long* __restrict__ acc,
                                                     const float* __restrict__ cb,
                                                     float* __restrict__ meanb,
                                                     float* __restrict__ rsb,
                                                     float* __restrict__ cnorm) {
  const int t = threadIdx.x;
  if (blockIdx.x == 0) {
    double s = (double)(long long)acc[t]       / (double)FIXSCALE;
    double q = (double)(long long)acc[256 + t] / (double)FIXSCALE;
    double mean = s / (double)NROW;
    double var  = q / (double)NROW - mean * mean;
    meanb[t] = (float)mean;
    rsb[t]   = (float)(1.0 / sqrt(var + (double)BN_EPS));
  } else {
    for (int code = t; code < K; code += 256) {
      const float* c = cb + (size_t)code * D;
      float s = 0.f;
      for (int dd = 0; dd < D; ++dd) s = fmaf(c[dd], c[dd], s);
      cnorm[code] = s;
    }
  }
}

// ---------------- kernel 2b: split codebook to fp16 hi/lo fragments ---------
// MFMA B-fragment: lane l holds code = nt*16 + (l&15), k = ks*32 + (l>>4)*8..+8
__global__ __launch_bounds__(64) void k_cbprep(const float* __restrict__ cb,
                                               _Float16* __restrict__ cbx) {
  const int nt = blockIdx.x;   // 0..19
  const int ks = blockIdx.y;   // 0..7
  const int l  = threadIdx.x;  // 0..63
  const int code = nt * 16 + (l & 15);
  const int d0 = ks * 32 + (l >> 4) * 8;
  const float* src = cb + (size_t)code * D + d0;
  const size_t bh = ((size_t)(nt * 2 + 0) * 8 + ks) * 512 + l * 8;
  const size_t bl = ((size_t)(nt * 2 + 1) * 8 + ks) * 512 + l * 8;
  #pragma unroll
  for (int j = 0; j < 8; ++j) {
    float v = src[j];
    _Float16 h = (_Float16)v;
    _Float16 lo = (_Float16)(v - (float)h);
    cbx[bh + j] = h;
    cbx[bl + j] = lo;
  }
}

// ---------------- kernel 3: A-in-regs (16 rows/wave), 16KB chunks, 4 blk/CU -
// 2048 blocks x 256 thr (4 waves). Wave wv owns rows row0 + wv*16..+16 vs ALL
// 320 codes. Chunk = 16 codes (16 KB); 2 LDS slots; reg-staged depth-2
// pipeline (R12-proven ordering). Small LDS (33 KB) -> 4 independent
// blocks/CU so barriers idle only 1/4 of the CU.
__global__ __launch_bounds__(256) void k_main(const float* __restrict__ x,
                                              const float* __restrict__ w,
                                              const float* __restrict__ bias,
                                              const float* __restrict__ cb,
                                              const float* __restrict__ meanb,
                                              const float* __restrict__ rsb,
                                              const float* __restrict__ cnorm,
                                              const _Float16* __restrict__ cbx,
                                              float* __restrict__ out) {
  __shared__ _Float16 Bbuf[2][8192];    // 2 x 16 KB chunk slots
  __shared__ float sxs[64];             // per-row |xb|^2
  __shared__ int bsel[64];

  const int t = threadIdx.x;
  const int lane = t & 63;
  const int wv = t >> 6;              // wave 0..3
  const int c15 = lane & 15;
  const int g = lane >> 4;
  const int row0 = (int)blockIdx.x * 64;

  // ---- staging: chunk c = 16 KB; 256 thr x 64 B = 4 x float4 per thread ----
  float4 s0, s1, s2, s3;
  const char* stg_src = (const char*)cbx + (size_t)t * 16;
#define ISSUE(c) {                                                  \
    const char* p_ = stg_src + (size_t)(c) * 16384;                 \
    s0 = *(const float4*)(p_);                                      \
    s1 = *(const float4*)(p_ + 4096);                               \
    s2 = *(const float4*)(p_ + 8192);                               \
    s3 = *(const float4*)(p_ + 12288);                              \
  }
#define WRITE(b) {                                                  \
    char* q_ = (char*)Bbuf[(b)] + t * 16;                           \
    *(float4*)(q_)         = s0;                                    \
    *(float4*)(q_ + 4096)  = s1;                                    \
    *(float4*)(q_ + 8192)  = s2;                                    \
    *(float4*)(q_ + 12288) = s3;                                    \
  }

  ISSUE(0);

  // ---- x -> A fragments in registers (normalize + fp16 hi/lo split) ----
  // lane l: row = row0 + wv*16 + (l&15), k-elems (l>>4)*8 + ks*32 .. +8
  half8 ah[8], al[8];
  float accq = 0.f;
  {
    const int arow = row0 + wv * 16 + c15;
    const int dbase = g * 8;
    const float* xp = x + (size_t)arow * D + dbase;
    #pragma unroll
    for (int ks = 0; ks < 8; ++ks) {
      const int d0 = dbase + ks * 32;
      float4 xa = *(const float4*)(xp + ks * 32);
      float4 xb2 = *(const float4*)(xp + ks * 32 + 4);
      float4 m0 = *(const float4*)(meanb + d0);
      float4 m1 = *(const float4*)(meanb + d0 + 4);
      float4 r0 = *(const float4*)(rsb + d0);
      float4 r1 = *(const float4*)(rsb + d0 + 4);
      float4 w0 = *(const float4*)(w + d0);
      float4 w1 = *(const float4*)(w + d0 + 4);
      float4 b0 = *(const float4*)(bias + d0);
      float4 b1 = *(const float4*)(bias + d0 + 4);
      float o0 = ((xa.x - m0.x) * r0.x) * w0.x + b0.x;
      float o1 = ((xa.y - m0.y) * r0.y) * w0.y + b0.y;
      float o2 = ((xa.z - m0.z) * r0.z) * w0.z + b0.z;
      float o3 = ((xa.w - m0.w) * r0.w) * w0.w + b0.w;
      float o4 = ((xb2.x - m1.x) * r1.x) * w1.x + b1.x;
      float o5 = ((xb2.y - m1.y) * r1.y) * w1.y + b1.y;
      float o6 = ((xb2.z - m1.z) * r1.z) * w1.z + b1.z;
      float o7 = ((xb2.w - m1.w) * r1.w) * w1.w + b1.w;
      accq = fmaf(o0, o0, accq); accq = fmaf(o1, o1, accq);
      accq = fmaf(o2, o2, accq); accq = fmaf(o3, o3, accq);
      accq = fmaf(o4, o4, accq); accq = fmaf(o5, o5, accq);
      accq = fmaf(o6, o6, accq); accq = fmaf(o7, o7, accq);
      _Float16 h;
      h = (_Float16)o0; ah[ks][0] = h; al[ks][0] = (_Float16)(o0 - (float)h);
      h = (_Float16)o1; ah[ks][1] = h; al[ks][1] = (_Float16)(o1 - (float)h);
      h = (_Float16)o2; ah[ks][2] = h; al[ks][2] = (_Float16)(o2 - (float)h);
      h = (_Float16)o3; ah[ks][3] = h; al[ks][3] = (_Float16)(o3 - (float)h);
      h = (_Float16)o4; ah[ks][4] = h; al[ks][4] = (_Float16)(o4 - (float)h);
      h = (_Float16)o5; ah[ks][5] = h; al[ks][5] = (_Float16)(o5 - (float)h);
      h = (_Float16)o6; ah[ks][6] = h; al[ks][6] = (_Float16)(o6 - (float)h);
      h = (_Float16)o7; ah[ks][7] = h; al[ks][7] = (_Float16)(o7 - (float)h);
    }
  }

  WRITE(0);                           // slot0 <- chunk0
  ISSUE(1);                           // chunk1 in flight

  // row sum: butterfly over the 4 k-slices (lanes xor 16, 32); deterministic
  {
    float v1 = accq + __shfl_xor(accq, 16);
    float sxrow = v1 + __shfl_xor(v1, 32);
    if (lane < 16) sxs[wv * 16 + lane] = sxrow;
  }
  __syncthreads();                    // slot0 + sxs visible

  // ---- chunk loop: 20 x (16 codes); argmin folded per chunk ----
  float bv[4];
  int   bix[4];
  #pragma unroll
  for (int r = 0; r < 4; ++r) { bv[r] = 3.4e38f; bix[r] = 0x7fffffff; }

  float sxr[4];
  #pragma unroll
  for (int r = 0; r < 4; ++r) sxr[r] = sxs[wv * 16 + g * 4 + r];

  for (int c = 0; c < 20; ++c) {
    // WRITE chunk c+1 (staged in regs last iter; readers of that slot done at
    // the prev barrier), then ISSUE chunk c+2 (flies under COMPUTE)
    if (c + 1 < 20) WRITE((c + 1) & 1);
    if (c + 2 < 20) ISSUE(c + 2);

    // COMPUTE chunk c from slot c&1
    {
      const _Float16* bb = Bbuf[c & 1] + lane * 8;
      f32x4 acc = (f32x4){0.f, 0.f, 0.f, 0.f};
      #pragma unroll
      for (int ks = 0; ks < 8; ++ks) {
        half8 bh = *(const half8*)(bb + ks * 512);          // hl=0
        half8 bl = *(const half8*)(bb + 4096 + ks * 512);   // hl=1
        acc = __builtin_amdgcn_mfma_f32_16x16x32_f16(ah[ks], bh, acc, 0, 0, 0);
        acc = __builtin_amdgcn_mfma_f32_16x16x32_f16(ah[ks], bl, acc, 0, 0, 0);
        acc = __builtin_amdgcn_mfma_f32_16x16x32_f16(al[ks], bh, acc, 0, 0, 0);
      }
      // d2 = (sx - 2*dot) + cn  (exact rounding-matched expression)
      // C/D layout: col = lane&15 (code), row = (lane>>4)*4 + r
      const int code = c * 16 + c15;
      const float cn = cnorm[code];
      #pragma unroll
      for (int r = 0; r < 4; ++r) {
        const float d2 = (sxr[r] - 2.0f * acc[r]) + cn;
        if (d2 < bv[r] || (d2 == bv[r] && code < bix[r])) { bv[r] = d2; bix[r] = code; }
      }
    }
    if (c < 19) __syncthreads();      // slot (c+1)&1 ready for next iteration
  }

  // ---- butterfly argmin across the 16 lanes (columns) ----
  #pragma unroll
  for (int off = 8; off >= 1; off >>= 1) {
    #pragma unroll
    for (int r = 0; r < 4; ++r) {
      const float ov = __shfl_xor(bv[r], off);
      const int   oi = __shfl_xor(bix[r], off);
      if (ov < bv[r] || (ov == bv[r] && oi < bix[r])) { bv[r] = ov; bix[r] = oi; }
    }
  }
  if (c15 == 0) {
    #pragma unroll
    for (int r = 0; r < 4; ++r) {
      const int row = wv * 16 + g * 4 + r;     // local row 0..63
      bsel[row] = bix[r];
      out[(size_t)NROW * D + row0 + row] = (float)bix[r];
    }
  }
  __syncthreads();

  // ---- gather chosen codes (exact f32 copy), 4 threads per row ----
  {
    const int lr = t >> 2;            // 0..63
    const int q = t & 3;
    const int code = bsel[lr];
    const float* cp = cb + (size_t)code * D;
    float* op = out + (size_t)(row0 + lr) * D;
    #pragma unroll
    for (int e = 0; e < 16; ++e) {
      *(float4*)(op + e * 16 + q * 4) = *(const float4*)(cp + e * 16 + q * 4);
    }
  }
#undef ISSUE
#undef WRITE
}

extern "C" void kernel_launch(void* const* d_in, const int* in_sizes, int n_in,
                              void* d_out, int out_size, void* d_ws, size_t ws_size,
                              hipStream_t stream) {
  const float* x    = (const float*)d_in[0];
  const float* w    = (const float*)d_in[1];
  const float* bias = (const float*)d_in[2];
  const float* cb   = (const float*)d_in[3];
  float* out = (float*)d_out;

  unsigned long long* acc = (unsigned long long*)d_ws;
  float* meanb = (float*)((char*)d_ws + 4096);
  float* rsb   = meanb + 256;
  float* cnorm = rsb + 256;
  _Float16* cbx = (_Float16*)((char*)d_ws + 8192);   // 320 KB

  k_zero<<<1, 256, 0, stream>>>(acc);
  k_cbprep<<<dim3(20, 8), 64, 0, stream>>>(cb, cbx);
  k_stats_partial<<<512, 256, 0, stream>>>(x, acc);
  k_stats_final<<<2, 256, 0, stream>>>(acc, cb, meanb, rsb, cnorm);
  k_main<<<NROW / 64, 256, 0, stream>>>(x, w, bias, cb, meanb, rsb, cnorm, cbx, out);
}